// Round 1
// baseline (482.594 us; speedup 1.0000x reference)
//
#include <hip/hip_runtime.h>
#include <hip/hip_bf16.h>
#include <math.h>

#define T_TOK 8192
#define DIM   1024
#define NEXP  8
#define FF    4096
#define BM    128
#define BN    128
#define BK    64
#define TPAD  (T_TOK + NEXP * BM)   // 9216 padded permuted rows

typedef __attribute__((ext_vector_type(4))) float  f32x4;
typedef __attribute__((ext_vector_type(8))) __bf16 bf16x8;

// ---------------- router: fp64 logits -> argmax + prob_max ----------------
__global__ void router_kernel(const float* __restrict__ x, const float* __restrict__ sw,
                              const float* __restrict__ sb, int* __restrict__ route,
                              float* __restrict__ scale, int* __restrict__ counts)
{
    int wave = threadIdx.x >> 6, lane = threadIdx.x & 63;
    int t = blockIdx.x * 4 + wave;
    const float* xr = x + (size_t)t * DIM;
    double acc[NEXP];
#pragma unroll
    for (int e = 0; e < NEXP; ++e) acc[e] = 0.0;
    for (int d = lane; d < DIM; d += 64) {
        double xv = (double)xr[d];
        const float* swr = sw + d * NEXP;
#pragma unroll
        for (int e = 0; e < NEXP; ++e) acc[e] += xv * (double)swr[e];
    }
#pragma unroll
    for (int e = 0; e < NEXP; ++e) {
        double v = acc[e];
        for (int off = 32; off; off >>= 1) v += __shfl_down(v, off);
        acc[e] = v;
    }
    if (lane == 0) {
        double m = -1e300; int am = 0;
#pragma unroll
        for (int e = 0; e < NEXP; ++e) {
            double v = acc[e] + (double)sb[e];
            acc[e] = v;
            if (v > m) { m = v; am = e; }
        }
        double s = 0.0;
#pragma unroll
        for (int e = 0; e < NEXP; ++e) s += exp(acc[e] - m);
        route[t] = am;
        scale[t] = (float)(1.0 / s);   // softmax max prob
        atomicAdd(&counts[am], 1);
    }
}

// ---------------- padded prefix sum over 8 experts ----------------
__global__ void offsets_kernel(const int* __restrict__ counts, int* __restrict__ offPad)
{
    int o = 0;
    for (int e = 0; e < NEXP; ++e) {
        offPad[e] = o;
        o += ((counts[e] + BM - 1) / BM) * BM;
    }
    offPad[NEXP] = o;
}

// ---------------- scatter token ids into padded per-expert segments ----------------
__global__ void scatter_kernel(const int* __restrict__ route, const int* __restrict__ offPad,
                               int* __restrict__ cursor, int* __restrict__ perm)
{
    int t = blockIdx.x * 256 + threadIdx.x;
    int e = route[t];
    int pos = atomicAdd(&cursor[e], 1);
    perm[offPad[e] + pos] = t;
}

// ---------------- x fp32 -> bf16 ----------------
__global__ void xcvt_kernel(const float* __restrict__ x, __hip_bfloat16* __restrict__ xb)
{
    size_t i = ((size_t)blockIdx.x * 256 + threadIdx.x) * 4;
    float4 v = *(const float4*)(x + i);
    __hip_bfloat16 t[4];
    t[0] = __float2bfloat16(v.x); t[1] = __float2bfloat16(v.y);
    t[2] = __float2bfloat16(v.z); t[3] = __float2bfloat16(v.w);
    *(uint2*)(xb + i) = *(uint2*)t;
}

// ---------------- batched [R][C] f32 -> [C][R] bf16 transpose ----------------
__global__ void transpose_cvt(const float* __restrict__ src, __hip_bfloat16* __restrict__ dst,
                              int R, int C)
{
    __shared__ float tile[32][33];
    size_t bofs = (size_t)blockIdx.z * (size_t)R * (size_t)C;
    src += bofs; dst += bofs;
    int c0 = blockIdx.x * 32, r0 = blockIdx.y * 32;
    int tx = threadIdx.x, ty = threadIdx.y;
#pragma unroll
    for (int i = 0; i < 32; i += 8)
        tile[ty + i][tx] = src[(size_t)(r0 + ty + i) * C + c0 + tx];
    __syncthreads();
#pragma unroll
    for (int i = 0; i < 32; i += 8)
        dst[(size_t)(c0 + ty + i) * R + r0 + tx] = __float2bfloat16(tile[tx][ty + i]);
}

// ---------------- async global -> LDS, 16B per lane ----------------
__device__ __forceinline__ void gl2lds16(const __hip_bfloat16* g, void* lds)
{
    __builtin_amdgcn_global_load_lds((const __attribute__((address_space(1))) void*)g,
                                     (__attribute__((address_space(3))) void*)lds, 16, 0, 0);
}

// ---------------- grouped GEMM, 128x128 tile, bf16 MFMA 16x16x32 ----------------
// MODE 0: h[row][f] = gelu(x[perm[row]] @ w1t[e]^T + b1[e])      (A gathered, K=1024, N=4096)
// MODE 1: out[perm[row]][d] = (h[row] @ w2t[e]^T + b2[e]) * scale (A direct,   K=4096, N=1024)
template<int MODE>
__global__ __launch_bounds__(256, 2) void moe_gemm(
    const __hip_bfloat16* __restrict__ A,
    const __hip_bfloat16* __restrict__ Bw,    // [E][N][K] (pre-transposed weights)
    const float* __restrict__ bias,           // [E][N]
    const int* __restrict__ offPad,           // [9]
    const int* __restrict__ perm,             // [TPAD]
    const float* __restrict__ scale,          // [T]
    __hip_bfloat16* __restrict__ Hout,        // MODE 0 output
    float* __restrict__ Out,                  // MODE 1 output
    int K, int N)
{
    const int m0 = blockIdx.y * BM;
    if (m0 >= offPad[NEXP]) return;
    int e = 0;
    while (offPad[e + 1] <= m0) ++e;
    const int nt = blockIdx.x;

    __shared__ short Asm[BM * BK];   // 16 KB
    __shared__ short Bsm[BN * BK];   // 16 KB  (row = n, col = k)

    const int tid  = threadIdx.x;
    const int lane = tid & 63;
    const int wid  = tid >> 6;

    const __hip_bfloat16* Bp = Bw + (size_t)e * (size_t)N * (size_t)K;
    size_t aoff[4], boff[4];
#pragma unroll
    for (int it = 0; it < 4; ++it) {
        int q = tid + it * 256;
        int r = q >> 3;
        int c = (q & 7) * 8;
        size_t row;
        if (MODE == 0) { int tk = perm[m0 + r]; row = (size_t)(tk < 0 ? 0 : tk); }
        else           { row = (size_t)(m0 + r); }
        aoff[it] = row * (size_t)K + c;
        boff[it] = (size_t)(nt * BN + r) * (size_t)K + c;
    }

    f32x4 acc[4][4];
#pragma unroll
    for (int i = 0; i < 4; ++i)
#pragma unroll
        for (int j = 0; j < 4; ++j) acc[i][j] = (f32x4)0.0f;

    const int wr = wid >> 1, wc = wid & 1;
    const int g  = lane >> 4, rl = lane & 15;

    for (int kt = 0; kt < K; kt += BK) {
#pragma unroll
        for (int it = 0; it < 4; ++it) {
            gl2lds16(A + aoff[it] + kt,  (char*)Asm + (it * 256 + wid * 64) * 16);
            gl2lds16(Bp + boff[it] + kt, (char*)Bsm + (it * 256 + wid * 64) * 16);
        }
        asm volatile("s_waitcnt vmcnt(0)" ::: "memory");
        __syncthreads();

#pragma unroll
        for (int kk = 0; kk < 2; ++kk) {
            bf16x8 af[4], bf[4];
#pragma unroll
            for (int m = 0; m < 4; ++m)
                af[m] = *(const bf16x8*)&Asm[(wr * 64 + m * 16 + rl) * BK + kk * 32 + g * 8];
#pragma unroll
            for (int n = 0; n < 4; ++n)
                bf[n] = *(const bf16x8*)&Bsm[(wc * 64 + n * 16 + rl) * BK + kk * 32 + g * 8];
#pragma unroll
            for (int m = 0; m < 4; ++m)
#pragma unroll
                for (int n = 0; n < 4; ++n)
                    acc[m][n] = __builtin_amdgcn_mfma_f32_16x16x32_bf16(af[m], bf[n], acc[m][n], 0, 0, 0);
        }
        __syncthreads();
    }

    const int colBase = nt * BN + wc * 64;
    const int rowBase = m0 + wr * 64;
    float bcol[4];
#pragma unroll
    for (int n = 0; n < 4; ++n) bcol[n] = bias[(size_t)e * N + colBase + n * 16 + rl];

    if (MODE == 0) {
#pragma unroll
        for (int m = 0; m < 4; ++m) {
#pragma unroll
            for (int r = 0; r < 4; ++r) {
                int row = rowBase + m * 16 + g * 4 + r;
                __hip_bfloat16* hrow = Hout + (size_t)row * N + colBase;
#pragma unroll
                for (int n = 0; n < 4; ++n) {
                    float v = acc[m][n][r] + bcol[n];
                    // gelu(v) = v * sigmoid(1.5957691 * (v + 0.044715 v^3))
                    float u = -1.5957691216057308f * (v + 0.044715f * v * v * v);
                    float gel = v / (1.f + __expf(u));
                    hrow[n * 16 + rl] = __float2bfloat16(gel);
                }
            }
        }
    } else {
#pragma unroll
        for (int m = 0; m < 4; ++m) {
#pragma unroll
            for (int r = 0; r < 4; ++r) {
                int row = rowBase + m * 16 + g * 4 + r;
                int tk = perm[row];
                if (tk >= 0) {
                    float sc = scale[tk];
                    float* orow = Out + (size_t)tk * N + colBase;
#pragma unroll
                    for (int n = 0; n < 4; ++n)
                        orow[n * 16 + rl] = (acc[m][n][r] + bcol[n]) * sc;
                }
            }
        }
    }
}

extern "C" void kernel_launch(void* const* d_in, const int* in_sizes, int n_in,
                              void* d_out, int out_size, void* d_ws, size_t ws_size,
                              hipStream_t stream)
{
    const float* x  = (const float*)d_in[0];
    const float* sw = (const float*)d_in[1];
    const float* sb = (const float*)d_in[2];
    const float* w1 = (const float*)d_in[3];
    const float* b1 = (const float*)d_in[4];
    const float* w2 = (const float*)d_in[5];
    const float* b2 = (const float*)d_in[6];
    float* out = (float*)d_out;
    char* ws = (char*)d_ws;

    // workspace layout (bytes)               size
    int*   counts = (int*)(ws + 0);        // 32
    int*   cursor = (int*)(ws + 256);      // 32
    int*   offPad = (int*)(ws + 512);      // 36
    int*   route  = (int*)(ws + 1024);     // 32768
    float* scale  = (float*)(ws + 33792);  // 32768
    int*   perm   = (int*)(ws + 66560);    // 36864
    __hip_bfloat16* xb  = (__hip_bfloat16*)(ws + 131072);    // 16.8 MB  [T][D]
    __hip_bfloat16* w1t = (__hip_bfloat16*)(ws + 16908288);  // 67.1 MB  [E][F][D]
    __hip_bfloat16* w2t = (__hip_bfloat16*)(ws + 84017152);  // 67.1 MB  [E][D][F]
    __hip_bfloat16* h   = (__hip_bfloat16*)(ws + 151126016); // 75.5 MB  [TPAD][F]
    // total ~216.1 MB

    hipMemsetAsync(ws, 0, 1024, stream);                 // counts/cursor/offPad
    hipMemsetAsync(perm, 0xFF, TPAD * 4, stream);        // perm = -1

    router_kernel<<<T_TOK / 4, 256, 0, stream>>>(x, sw, sb, route, scale, counts);
    offsets_kernel<<<1, 1, 0, stream>>>(counts, offPad);
    scatter_kernel<<<T_TOK / 256, 256, 0, stream>>>(route, offPad, cursor, perm);
    xcvt_kernel<<<(T_TOK * DIM) / 1024, 256, 0, stream>>>(x, xb);
    dim3 tb(32, 8);
    transpose_cvt<<<dim3(FF / 32, DIM / 32, NEXP), tb, 0, stream>>>(w1, w1t, DIM, FF);
    transpose_cvt<<<dim3(DIM / 32, FF / 32, NEXP), tb, 0, stream>>>(w2, w2t, FF, DIM);

    moe_gemm<0><<<dim3(FF / BN, TPAD / BM), 256, 0, stream>>>(
        xb, w1t, b1, offPad, perm, scale, h, nullptr, DIM, FF);
    moe_gemm<1><<<dim3(DIM / BN, TPAD / BM), 256, 0, stream>>>(
        h, w2t, b2, offPad, perm, scale, nullptr, out, FF, DIM);
}

// Round 2
// 444.327 us; speedup vs baseline: 1.0861x; 1.0861x over previous
//
#include <hip/hip_runtime.h>
#include <hip/hip_bf16.h>
#include <math.h>

#define T_TOK 8192
#define DIM   1024
#define NEXP  8
#define FF    4096
#define BM    256
#define BN    256
#define BK    64
#define TPAD  (T_TOK + NEXP * BM)   // 10240 padded permuted rows

typedef __attribute__((ext_vector_type(4))) float  f32x4;
typedef __attribute__((ext_vector_type(8))) __bf16 bf16x8;

// ---------------- router: fp64 logits -> argmax + prob_max ----------------
__global__ void router_kernel(const float* __restrict__ x, const float* __restrict__ sw,
                              const float* __restrict__ sb, int* __restrict__ route,
                              float* __restrict__ scale, int* __restrict__ counts)
{
    int wave = threadIdx.x >> 6, lane = threadIdx.x & 63;
    int t = blockIdx.x * 4 + wave;
    const float* xr = x + (size_t)t * DIM;
    double acc[NEXP];
#pragma unroll
    for (int e = 0; e < NEXP; ++e) acc[e] = 0.0;
    for (int d = lane; d < DIM; d += 64) {
        double xv = (double)xr[d];
        const float* swr = sw + d * NEXP;
#pragma unroll
        for (int e = 0; e < NEXP; ++e) acc[e] += xv * (double)swr[e];
    }
#pragma unroll
    for (int e = 0; e < NEXP; ++e) {
        double v = acc[e];
        for (int off = 32; off; off >>= 1) v += __shfl_down(v, off);
        acc[e] = v;
    }
    if (lane == 0) {
        double m = -1e300; int am = 0;
#pragma unroll
        for (int e = 0; e < NEXP; ++e) {
            double v = acc[e] + (double)sb[e];
            acc[e] = v;
            if (v > m) { m = v; am = e; }
        }
        double s = 0.0;
#pragma unroll
        for (int e = 0; e < NEXP; ++e) s += exp(acc[e] - m);
        route[t] = am;
        scale[t] = (float)(1.0 / s);
        atomicAdd(&counts[am], 1);
    }
}

// ---------------- padded prefix sum over 8 experts (pad to BM=256) ----------------
__global__ void offsets_kernel(const int* __restrict__ counts, int* __restrict__ offPad)
{
    int o = 0;
    for (int e = 0; e < NEXP; ++e) {
        offPad[e] = o;
        o += ((counts[e] + BM - 1) / BM) * BM;
    }
    offPad[NEXP] = o;
}

// ---------------- scatter token ids into padded per-expert segments ----------------
__global__ void scatter_kernel(const int* __restrict__ route, const int* __restrict__ offPad,
                               int* __restrict__ cursor, int* __restrict__ perm)
{
    int t = blockIdx.x * 256 + threadIdx.x;
    int e = route[t];
    int pos = atomicAdd(&cursor[e], 1);
    perm[offPad[e] + pos] = t;
}

// ---------------- x fp32 -> bf16 ----------------
__global__ void xcvt_kernel(const float* __restrict__ x, __hip_bfloat16* __restrict__ xb)
{
    size_t i = ((size_t)blockIdx.x * 256 + threadIdx.x) * 4;
    float4 v = *(const float4*)(x + i);
    __hip_bfloat16 t[4];
    t[0] = __float2bfloat16(v.x); t[1] = __float2bfloat16(v.y);
    t[2] = __float2bfloat16(v.z); t[3] = __float2bfloat16(v.w);
    *(uint2*)(xb + i) = *(uint2*)t;
}

// ---------------- batched [R][C] f32 -> [C][R] bf16 transpose, 64x64 tiles ----------------
__global__ __launch_bounds__(256) void transpose_cvt64(const float* __restrict__ src,
                                                       __hip_bfloat16* __restrict__ dst,
                                                       int R, int C)
{
    __shared__ float tile[64][65];
    size_t bofs = (size_t)blockIdx.z * (size_t)R * (size_t)C;
    int c0 = blockIdx.x * 64, r0 = blockIdx.y * 64;
    int t = threadIdx.x;
    int tx = t & 15, ty = t >> 4;       // tx: float4 col, ty: row base
#pragma unroll
    for (int i = 0; i < 4; ++i) {
        int r = ty + i * 16;
        float4 v = *(const float4*)(src + bofs + (size_t)(r0 + r) * C + c0 + tx * 4);
        tile[r][tx * 4 + 0] = v.x; tile[r][tx * 4 + 1] = v.y;
        tile[r][tx * 4 + 2] = v.z; tile[r][tx * 4 + 3] = v.w;
    }
    __syncthreads();
#pragma unroll
    for (int i = 0; i < 4; ++i) {
        int oc = ty + i * 16;           // dst row = src col
        __hip_bfloat16 u[4];
#pragma unroll
        for (int j = 0; j < 4; ++j)
            u[j] = __float2bfloat16(tile[tx * 4 + j][oc]);
        *(uint2*)(dst + bofs + (size_t)(c0 + oc) * R + r0 + tx * 4) = *(uint2*)u;
    }
}

// =====================================================================
// 256x256 8-phase grouped GEMM (T2 swizzle + T3/T4 counted vmcnt + T5)
// MODE 0: h = gelu(x[perm] @ w1t^T + b1)   K=1024, N=4096
// MODE 1: out[perm] = (h @ w2t^T + b2)*sc  K=4096, N=1024
// =====================================================================
#define STAGE_A(b, h, t) do { \
    __builtin_amdgcn_global_load_lds((const __attribute__((address_space(1))) void*)(aSrc[h][0] + (size_t)(t) * 64), \
        (__attribute__((address_space(3))) void*)(ldsA + (b) * 32768 + (h) * 16384 + wid * 1024), 16, 0, 0); \
    __builtin_amdgcn_global_load_lds((const __attribute__((address_space(1))) void*)(aSrc[h][1] + (size_t)(t) * 64), \
        (__attribute__((address_space(3))) void*)(ldsA + (b) * 32768 + (h) * 16384 + (wid + 8) * 1024), 16, 0, 0); \
} while (0)

#define STAGE_B(b, h, t) do { \
    __builtin_amdgcn_global_load_lds((const __attribute__((address_space(1))) void*)(bSrc[h][0] + (size_t)(t) * 64), \
        (__attribute__((address_space(3))) void*)(ldsB + (b) * 32768 + (h) * 16384 + wid * 1024), 16, 0, 0); \
    __builtin_amdgcn_global_load_lds((const __attribute__((address_space(1))) void*)(bSrc[h][1] + (size_t)(t) * 64), \
        (__attribute__((address_space(3))) void*)(ldsB + (b) * 32768 + (h) * 16384 + (wid + 8) * 1024), 16, 0, 0); \
} while (0)

#define VMW asm volatile("s_waitcnt vmcnt(4)" ::: "memory")

#define PHASE(B_, MH, KS, LOADB, STAGEX, VMX) do { \
    __builtin_amdgcn_sched_barrier(0); \
    bf16x8 af[4]; \
    _Pragma("unroll") \
    for (int i_ = 0; i_ < 4; ++i_) \
        af[i_] = *(const bf16x8*)(aRd + (B_) * 32768 + ((MH) * 4 + i_) * 2048 + kOff[KS]); \
    if (LOADB) { \
        _Pragma("unroll") \
        for (int n_ = 0; n_ < 4; ++n_) \
            bfr[KS][n_] = *(const bf16x8*)(bRd + (B_) * 32768 + n_ * 2048 + kOff[KS]); \
    } \
    STAGEX; \
    __builtin_amdgcn_s_barrier(); \
    asm volatile("s_waitcnt lgkmcnt(0)" ::: "memory"); \
    __builtin_amdgcn_sched_barrier(0); \
    __builtin_amdgcn_s_setprio(1); \
    _Pragma("unroll") \
    for (int i_ = 0; i_ < 4; ++i_) \
        _Pragma("unroll") \
        for (int n_ = 0; n_ < 4; ++n_) \
            acc[(MH) * 4 + i_][n_] = __builtin_amdgcn_mfma_f32_16x16x32_bf16(af[i_], bfr[KS][n_], acc[(MH) * 4 + i_][n_], 0, 0, 0); \
    __builtin_amdgcn_s_setprio(0); \
    VMX; \
    __builtin_amdgcn_s_barrier(); \
} while (0)

template<int MODE>
__global__ __launch_bounds__(512, 2) void moe_gemm8(
    const __hip_bfloat16* __restrict__ A,
    const __hip_bfloat16* __restrict__ Bw,    // [E][N][K]
    const float* __restrict__ bias,           // [E][N]
    const int* __restrict__ offPad,
    const int* __restrict__ perm,
    const float* __restrict__ scale,
    __hip_bfloat16* __restrict__ Hout,
    float* __restrict__ Out,
    const int K, const int N)
{
    // XCD-bijective block swizzle (nwg % 8 == 0 for both launches)
    const int nwg = gridDim.x * gridDim.y;
    const int bid = blockIdx.y * gridDim.x + blockIdx.x;
    const int swz = (bid & 7) * (nwg >> 3) + (bid >> 3);
    const int nt = swz % gridDim.x;
    const int mt = swz / gridDim.x;
    const int m0 = mt * BM;
    if (m0 >= offPad[NEXP]) return;
    int e = 0;
    while (offPad[e + 1] <= m0) ++e;

    __shared__ char lds[131072];
    char* ldsA = lds;               // [2 buf][2 half][128 rows][128 B]
    char* ldsB = lds + 65536;

    const int tid  = threadIdx.x;
    const int lane = tid & 63;
    const int wid  = tid >> 6;      // 0..7
    const int wr   = wid >> 2;      // 0..1  (M half)
    const int wc   = wid & 3;       // 0..3  (N quarter)
    const int g    = lane >> 4, rl = lane & 15;

    const __hip_bfloat16* Bp = Bw + (size_t)e * (size_t)N * (size_t)K;

    // ---- staging source pointers (per thread, fixed rows; swizzle pre-applied) ----
    const int l3 = lane >> 3;                    // row within 8-row chunk
    const int colOff = ((lane & 7) ^ l3) * 8;    // inverse-swizzled col block (bf16 elems)
    const __hip_bfloat16* aSrc[2][2];
    const __hip_bfloat16* bSrc[2][2];
#pragma unroll
    for (int h = 0; h < 2; ++h)
#pragma unroll
        for (int j = 0; j < 2; ++j) {
            int r = (wid + j * 8) * 8 + l3;      // 0..127 row in half
            int arow = m0 + h * 128 + r;
            size_t ar;
            if (MODE == 0) { int tk = perm[arow]; ar = (size_t)(tk < 0 ? 0 : tk); }
            else           { ar = (size_t)arow; }
            aSrc[h][j] = A + ar * (size_t)K + colOff;
            bSrc[h][j] = Bp + (size_t)(nt * BN + h * 128 + r) * (size_t)K + colOff;
        }

    // ---- fragment read bases (swizzled) ----
    const char* aRd = ldsA + wr * 16384 + rl * 128;
    const char* bRd = ldsB + (wc >> 1) * 16384 + (wc & 1) * 8192 + rl * 128;
    int kOff[2];
    kOff[0] = ((0 * 4 + g) ^ (rl & 7)) * 16;
    kOff[1] = ((1 * 4 + g) ^ (rl & 7)) * 16;

    f32x4 acc[8][4];
#pragma unroll
    for (int i = 0; i < 8; ++i)
#pragma unroll
        for (int n = 0; n < 4; ++n) acc[i][n] = (f32x4)0.0f;
    bf16x8 bfr[2][4];

    const int ntiles = K >> 6;

    // ---- prologue: T0 (all 4 halves) + T1.B (2 halves) ----
    STAGE_A(0, 0, 0); STAGE_A(0, 1, 0);
    STAGE_B(0, 0, 0); STAGE_B(0, 1, 0);
    {
        int t1p = 1 < ntiles ? 1 : ntiles - 1;
        STAGE_B(1, 0, t1p); STAGE_B(1, 1, t1p);
    }
    asm volatile("s_waitcnt vmcnt(4)" ::: "memory");
    __builtin_amdgcn_s_barrier();

    for (int it = 0; it < (ntiles >> 1); ++it) {
        const int t1 = 2 * it + 1;
        const int t2 = 2 * it + 2 < ntiles ? 2 * it + 2 : ntiles - 1;
        const int t3 = 2 * it + 3 < ntiles ? 2 * it + 3 : ntiles - 1;
        PHASE(0, 0, 0, true,  STAGE_A(1, 0, t1), );
        PHASE(0, 0, 1, true,  STAGE_A(1, 1, t1), );
        PHASE(0, 1, 0, false, STAGE_B(0, 0, t2), );
        PHASE(0, 1, 1, false, STAGE_B(0, 1, t2), VMW);
        PHASE(1, 0, 0, true,  STAGE_A(0, 0, t2), );
        PHASE(1, 0, 1, true,  STAGE_A(0, 1, t2), );
        PHASE(1, 1, 0, false, STAGE_B(1, 0, t3), );
        PHASE(1, 1, 1, false, STAGE_B(1, 1, t3), VMW);
    }
    asm volatile("s_waitcnt vmcnt(0)" ::: "memory");  // drain before LDS dealloc

    // ---- epilogue ----
    const int colBase = nt * BN + wc * 64;
    const int rowBase = m0 + wr * 128;
    float bcol[4];
#pragma unroll
    for (int n = 0; n < 4; ++n) bcol[n] = bias[(size_t)e * N + colBase + n * 16 + rl];

    if (MODE == 0) {
#pragma unroll
        for (int m = 0; m < 8; ++m) {
#pragma unroll
            for (int r = 0; r < 4; ++r) {
                int row = rowBase + m * 16 + g * 4 + r;
                __hip_bfloat16* hrow = Hout + (size_t)row * N + colBase;
#pragma unroll
                for (int n = 0; n < 4; ++n) {
                    float v = acc[m][n][r] + bcol[n];
                    float u = -1.5957691216057308f * (v + 0.044715f * v * v * v);
                    float gel = v / (1.f + __expf(u));
                    hrow[n * 16 + rl] = __float2bfloat16(gel);
                }
            }
        }
    } else {
#pragma unroll
        for (int m = 0; m < 8; ++m) {
#pragma unroll
            for (int r = 0; r < 4; ++r) {
                int row = rowBase + m * 16 + g * 4 + r;
                int tk = perm[row];
                if (tk >= 0) {
                    float sc = scale[tk];
                    float* orow = Out + (size_t)tk * N + colBase;
#pragma unroll
                    for (int n = 0; n < 4; ++n)
                        orow[n * 16 + rl] = (acc[m][n][r] + bcol[n]) * sc;
                }
            }
        }
    }
}

extern "C" void kernel_launch(void* const* d_in, const int* in_sizes, int n_in,
                              void* d_out, int out_size, void* d_ws, size_t ws_size,
                              hipStream_t stream)
{
    const float* x  = (const float*)d_in[0];
    const float* sw = (const float*)d_in[1];
    const float* sb = (const float*)d_in[2];
    const float* w1 = (const float*)d_in[3];
    const float* b1 = (const float*)d_in[4];
    const float* w2 = (const float*)d_in[5];
    const float* b2 = (const float*)d_in[6];
    float* out = (float*)d_out;
    char* ws = (char*)d_ws;

    // workspace layout (bytes)
    int*   counts = (int*)(ws + 0);
    int*   cursor = (int*)(ws + 256);
    int*   offPad = (int*)(ws + 512);
    int*   route  = (int*)(ws + 4096);      // 32 KB
    float* scale  = (float*)(ws + 36864);   // 32 KB
    int*   perm   = (int*)(ws + 69632);     // 40 KB
    __hip_bfloat16* xb  = (__hip_bfloat16*)(ws + 131072);    // 16.8 MB [T][D]
    __hip_bfloat16* w1t = (__hip_bfloat16*)(ws + 16908288);  // 67.1 MB [E][F][D]
    __hip_bfloat16* w2t = (__hip_bfloat16*)(ws + 16908288);  // aliased: written AFTER gemm1
    __hip_bfloat16* h   = (__hip_bfloat16*)(ws + 84017152);  // 83.9 MB [TPAD][F]
    // total ~160.1 MB

    hipMemsetAsync(ws, 0, 1024, stream);
    hipMemsetAsync(perm, 0xFF, TPAD * 4, stream);

    router_kernel<<<T_TOK / 4, 256, 0, stream>>>(x, sw, sb, route, scale, counts);
    offsets_kernel<<<1, 1, 0, stream>>>(counts, offPad);
    scatter_kernel<<<T_TOK / 256, 256, 0, stream>>>(route, offPad, cursor, perm);
    xcvt_kernel<<<(T_TOK * DIM) / 1024, 256, 0, stream>>>(x, xb);

    transpose_cvt64<<<dim3(FF / 64, DIM / 64, NEXP), 256, 0, stream>>>(w1, w1t, DIM, FF);

    moe_gemm8<0><<<dim3(FF / BN, TPAD / BM), 512, 0, stream>>>(
        xb, w1t, b1, offPad, perm, scale, h, nullptr, DIM, FF);

    transpose_cvt64<<<dim3(DIM / 64, FF / 64, NEXP), 256, 0, stream>>>(w2, w2t, FF, DIM);

    moe_gemm8<1><<<dim3(DIM / BN, TPAD / BM), 512, 0, stream>>>(
        h, w2t, b2, offPad, perm, scale, nullptr, out, FF, DIM);
}